// Round 2
// baseline (614.374 us; speedup 1.0000x reference)
//
#include <hip/hip_runtime.h>

#define BB 16
#define CC 384
#define CH 64
#define CF 193
#define HW 16384   // 128*128

// ---------------- Kernel 1: global average pool ----------------
// x: [B, C, H, W] fp32, each plane of 16384 floats contiguous (64 KB).
// One block per plane, 256 threads, float4 loads (16 iters).
__global__ __launch_bounds__(256) void pool_kernel(const float4* __restrict__ x,
                                                   float* __restrict__ y0) {
    const int plane = blockIdx.x;                 // b*C + c
    const float4* p = x + (size_t)plane * (HW / 4);
    const int t = threadIdx.x;

    float s = 0.f;
#pragma unroll
    for (int r = 0; r < HW / 4 / 256; ++r) {      // 16 iterations
        float4 v = p[t + 256 * r];
        s += v.x + v.y + v.z + v.w;
    }

    // wave64 reduce
#pragma unroll
    for (int off = 32; off > 0; off >>= 1) s += __shfl_down(s, off);

    __shared__ float red[4];
    const int wid = t >> 6, lane = t & 63;
    if (lane == 0) red[wid] = s;
    __syncthreads();
    if (t == 0) {
        float tot = red[0] + red[1] + red[2] + red[3];
        y0[plane] = tot * (1.0f / (float)HW);
    }
}

// ---------------- Kernel 2: the head (all the tiny math) ----------------
// One block per batch element, 384 threads.
__global__ __launch_bounds__(384) void head_kernel(
    const float* __restrict__ y0g,
    const float* __restrict__ W1,  const float* __restrict__ b1,
    const float* __restrict__ W2,  const float* __restrict__ b2,
    const float* __restrict__ Ws1, const float* __restrict__ bs1,
    const float* __restrict__ Ws2, const float* __restrict__ bs2,
    float* __restrict__ out)
{
    __shared__ float y0[CC], h[CH], y[CC];
    __shared__ float ct[CC], st[CC];
    __shared__ float rr[CF], ri[CF];

    const int b = blockIdx.x, t = threadIdx.x;

    // stage y0 + twiddle tables (cos/sin of 2*pi*t/384)
    y0[t] = y0g[b * CC + t];
    {
        float ang = (float)t * (6.283185307179586f / (float)CC);
        float sv, cv;
        sincosf(ang, &sv, &cv);
        st[t] = sv; ct[t] = cv;
    }
    __syncthreads();

    // h = relu(y0 @ W1c^T + b1), W1c[j,c] = W1[(j*384+c)*9+4]
    if (t < CH) {
        float acc = b1[t];
        const float* w = W1 + (size_t)t * CC * 9 + 4;
        for (int c = 0; c < CC; ++c) acc += y0[c] * w[c * 9];
        h[t] = fmaxf(acc, 0.f);
    }
    __syncthreads();

    // y = sigmoid(h @ W2c^T + b2), W2c[c,j] = W2[(c*64+j)*9+4]
    {
        float acc = b2[t];
        const float* w = W2 + (size_t)t * CH * 9 + 4;
        for (int j = 0; j < CH; ++j) acc += h[j] * w[j * 9];
        y[t] = 1.f / (1.f + expf(-acc));
    }
    __syncthreads();

    // s1/s2 projections + rfft bin (thread t = bin k, t < 193)
    if (t < CF) {
        const float* w1r = Ws1 + (size_t)t * CC;
        const float* w2r = Ws2 + (size_t)t * CC;
        float a1 = bs1[t], a2 = bs2[t];
        float re = 0.f, im = 0.f;
        int m = 0;                                 // (t*c) % 384
        for (int c = 0; c < CC; ++c) {
            float yc = y[c];
            a1 += yc * w1r[c];
            a2 += yc * w2r[c];
            re += yc * ct[m];
            im -= yc * st[m];
            m += t; if (m >= CC) m -= CC;          // t < 384 so one subtract suffices
        }
        a1 = fmaxf(a1, 0.f);
        a2 = fmaxf(a2, 0.f);
        float amp = sqrtf(re * re + im * im) * a1;
        float pha = atan2f(im, re) * a2;
        float sp, cp;
        sincosf(pha, &sp, &cp);
        rr[t] = amp * cp;
        ri[t] = amp * sp;
    }
    __syncthreads();

    // irfft (real formula; Im of DC/Nyquist dropped, matching numpy) + final mul
    {
        float acc = 0.f;
        int m = 0;                                 // (k*t) % 384, k loop below
        for (int k = 1; k < 192; ++k) {
            m += t; if (m >= CC) m -= CC;
            acc += rr[k] * ct[m] - ri[k] * st[m];
        }
        float nyq = (t & 1) ? -rr[192] : rr[192];
        float xr = (rr[0] + 2.f * acc + nyq) * (1.0f / (float)CC);
        out[b * CC + t] = xr * y[t];
    }
}

extern "C" void kernel_launch(void* const* d_in, const int* in_sizes, int n_in,
                              void* d_out, int out_size, void* d_ws, size_t ws_size,
                              hipStream_t stream) {
    const float4* x = (const float4*)d_in[0];
    const float* W1  = (const float*)d_in[1];
    const float* b1  = (const float*)d_in[2];
    const float* W2  = (const float*)d_in[3];
    const float* b2  = (const float*)d_in[4];
    const float* Ws1 = (const float*)d_in[5];
    const float* bs1 = (const float*)d_in[6];
    const float* Ws2 = (const float*)d_in[7];
    const float* bs2 = (const float*)d_in[8];
    float* out = (float*)d_out;

    float* y0 = (float*)d_ws;   // 6144 floats

    pool_kernel<<<BB * CC, 256, 0, stream>>>(x, y0);
    head_kernel<<<BB, 384, 0, stream>>>(y0, W1, b1, W2, b2, Ws1, bs1, Ws2, bs2, out);
}